// Round 1
// baseline (31109.891 us; speedup 1.0000x reference)
//
#include <hip/hip_runtime.h>
#include <hip/hip_bf16.h>
#include <hip/hip_cooperative_groups.h>

namespace cg = cooperative_groups;

#define TT 512
#define BB 64
#define II 256
#define HH 1024
#define NJ 4            // hidden units per WG
#define ROWS 16         // gate rows per WG (4 gates * NJ)
#define KTOT 1280       // 256 (x) + 1024 (h)
#define KPAD 1288       // +8 bf16 pad to break LDS bank conflicts
#define NWG 256

typedef __bf16 bf16x8 __attribute__((ext_vector_type(8)));
typedef float f32x4 __attribute__((ext_vector_type(4)));

// ---------------- prep kernels ----------------

__global__ __launch_bounds__(256) void k_cast_inputs(const float* __restrict__ in,
                                                     __hip_bfloat16* __restrict__ outp) {
  int i = (blockIdx.x * 256 + threadIdx.x) * 4;   // grid covers exactly B*T*I
  float4 v = *reinterpret_cast<const float4*>(in + i);
  outp[i + 0] = __float2bfloat16(v.x);
  outp[i + 1] = __float2bfloat16(v.y);
  outp[i + 2] = __float2bfloat16(v.z);
  outp[i + 3] = __float2bfloat16(v.w);
}

// Pack W rows: packed row p = wg*16 + gate*4 + jj  (j = wg*4 + jj), cols [0:256)=Wx, [256:1280)=Wh
__global__ __launch_bounds__(256) void k_pack_w(
    const float* __restrict__ wxi, const float* __restrict__ whi,
    const float* __restrict__ wxf, const float* __restrict__ whf,
    const float* __restrict__ wxg, const float* __restrict__ whg,
    const float* __restrict__ wxo, const float* __restrict__ who,
    __hip_bfloat16* __restrict__ Wp) {
  int t = blockIdx.x * 256 + threadIdx.x;   // 0 .. 4096*320
  int p = t / 320;
  int k4 = (t - p * 320) * 4;
  int wg = p >> 4, loc = p & 15, gate = loc >> 2, jj = loc & 3;
  int j = wg * NJ + jj;
  const float* wx = (gate == 0) ? wxi : (gate == 1) ? wxf : (gate == 2) ? wxg : wxo;
  const float* wh = (gate == 0) ? whi : (gate == 1) ? whf : (gate == 2) ? whg : who;
  float4 v;
  if (k4 < II) v = *reinterpret_cast<const float4*>(wx + (size_t)j * II + k4);
  else         v = *reinterpret_cast<const float4*>(wh + (size_t)j * HH + (k4 - II));
  __hip_bfloat16* o = Wp + (size_t)p * KTOT + k4;
  o[0] = __float2bfloat16(v.x);
  o[1] = __float2bfloat16(v.y);
  o[2] = __float2bfloat16(v.z);
  o[3] = __float2bfloat16(v.w);
}

__global__ __launch_bounds__(256) void k_pack_bias_h0(
    const float* __restrict__ bii, const float* __restrict__ bhi,
    const float* __restrict__ bif, const float* __restrict__ bhf,
    const float* __restrict__ bg,  const float* __restrict__ bhg,
    const float* __restrict__ bio, const float* __restrict__ bho,
    const float* __restrict__ h0, float* __restrict__ biasp,
    __hip_bfloat16* __restrict__ hb) {
  int i = blockIdx.x * 256 + threadIdx.x;   // 0..65535
  if (i < 4096) {
    int wg = i >> 4, loc = i & 15, gate = loc >> 2, jj = loc & 3;
    int j = wg * NJ + jj;
    const float* bi = (gate == 0) ? bii : (gate == 1) ? bif : (gate == 2) ? bg : bio;
    const float* bh = (gate == 0) ? bhi : (gate == 1) ? bhf : (gate == 2) ? bhg : bho;
    biasp[i] = bi[j] + bh[j];
  }
  hb[i] = __float2bfloat16(h0[i]);   // h0 is (1,B,H) = 65536 elems
}

// ---------------- persistent recurrent kernel ----------------
// Grid = 256 WGs x 256 threads (4 waves). WG wg owns j in [wg*4, wg*4+4),
// i.e. packed gate rows [wg*16, wg*16+16). Weights resident in LDS all 512 steps.
// Per step: z = [x_t ; h] @ Wslice^T via MFMA, then per-thread gate math,
// c in registers, h ping-pong in global bf16, grid.sync().

__global__ __launch_bounds__(256) void k_lstm(
    const __hip_bfloat16* __restrict__ xb,   // (B,T,I) bf16
    const __hip_bfloat16* __restrict__ Wp,   // (4096,1280) packed bf16
    const float* __restrict__ biasp,         // (4096)
    const float* __restrict__ c0,            // (B,H) f32
    __hip_bfloat16* __restrict__ hbuf,       // 2 x (B,H) bf16 ping-pong
    float* __restrict__ out)                 // hidden(B,T,H) + h(B,H) + c(B,H)
{
  __shared__ __align__(16) ushort Wl[ROWS][KPAD];   // 41216 B
  __shared__ float zl[BB][ROWS + 1];                // 4352 B

  const int wg = blockIdx.x;
  const int tid = threadIdx.x;
  const int lane = tid & 63;
  const int wave = tid >> 6;

  // stage this WG's 16 weight rows into LDS (once)
  const __hip_bfloat16* Wsrc = Wp + (size_t)wg * ROWS * KTOT;
  for (int v = tid; v < ROWS * (KTOT / 8); v += 256) {
    int r = v / (KTOT / 8);
    int kc = v - r * (KTOT / 8);
    *reinterpret_cast<uint4*>(&Wl[r][kc * 8]) =
        *reinterpret_cast<const uint4*>(Wsrc + (size_t)r * KTOT + kc * 8);
  }

  // epilogue identity: thread -> one (batch, jj) cell
  const int b_e = tid >> 2;        // 0..63
  const int jj_e = tid & 3;        // 0..3
  const int j_e = wg * NJ + jj_e;  // global hidden index
  float c_reg = c0[b_e * HH + j_e];
  const float bias_i = biasp[wg * ROWS + 0 * NJ + jj_e];
  const float bias_f = biasp[wg * ROWS + 1 * NJ + jj_e];
  const float bias_g = biasp[wg * ROWS + 2 * NJ + jj_e];
  const float bias_o = biasp[wg * ROWS + 3 * NJ + jj_e];

  // MFMA lane geometry (16x16x32: A row=lane&15, k=8*(lane>>4)+e; D col=lane&15, row=4*(lane>>4)+reg)
  const int mrow = wave * 16 + (lane & 15);      // batch row of A
  const int kq = (lane >> 4) * 8;                // k sub-offset
  const int ncol = lane & 15;                    // gate-row (B column)
  const int drow0 = wave * 16 + (lane >> 4) * 4; // D row base

  const __hip_bfloat16* xrow = xb + (size_t)mrow * (TT * II);

  __syncthreads();

  cg::grid_group grid = cg::this_grid();
  int cur = 0;

  for (int t = 0; t < TT; ++t) {
    f32x4 accs[4];
    #pragma unroll
    for (int q = 0; q < 4; ++q) accs[q] = (f32x4){0.f, 0.f, 0.f, 0.f};

    const __hip_bfloat16* xp = xrow + t * II + kq;
    const __hip_bfloat16* hp = hbuf + cur * (BB * HH) + mrow * HH + kq;

    // x part: K = 0..255
    #pragma unroll
    for (int kk = 0; kk < 8; ++kk) {
      bf16x8 a = *reinterpret_cast<const bf16x8*>(xp + kk * 32);
      bf16x8 b = *reinterpret_cast<const bf16x8*>(&Wl[ncol][kk * 32 + kq]);
      accs[kk & 3] = __builtin_amdgcn_mfma_f32_16x16x32_bf16(a, b, accs[kk & 3], 0, 0, 0);
    }
    // h part: K = 256..1279
    #pragma unroll
    for (int kk = 0; kk < 32; ++kk) {
      bf16x8 a = *reinterpret_cast<const bf16x8*>(hp + kk * 32);
      bf16x8 b = *reinterpret_cast<const bf16x8*>(&Wl[ncol][II + kk * 32 + kq]);
      accs[kk & 3] = __builtin_amdgcn_mfma_f32_16x16x32_bf16(a, b, accs[kk & 3], 0, 0, 0);
    }
    f32x4 acc = (accs[0] + accs[1]) + (accs[2] + accs[3]);

    #pragma unroll
    for (int r = 0; r < 4; ++r) zl[drow0 + r][ncol] = acc[r];
    __syncthreads();

    // gate math: one thread per (b, jj)
    float zi = zl[b_e][0 + jj_e] + bias_i;
    float zf = zl[b_e][4 + jj_e] + bias_f;
    float zg = zl[b_e][8 + jj_e] + bias_g;
    float zo = zl[b_e][12 + jj_e] + bias_o;
    float ig = 1.f / (1.f + __expf(-zi));
    float fg = 1.f / (1.f + __expf(-zf));
    float gg = 2.f / (1.f + __expf(-2.f * zg)) - 1.f;   // tanh
    float og = 1.f / (1.f + __expf(-zo));
    c_reg = fg * c_reg + ig * gg;
    float tc = 2.f / (1.f + __expf(-2.f * c_reg)) - 1.f;
    float h = og * tc;

    out[(size_t)b_e * (TT * HH) + (size_t)t * HH + j_e] = h;
    hbuf[(cur ^ 1) * (BB * HH) + b_e * HH + j_e] = __float2bfloat16(h);
    if (t == TT - 1) {
      out[(size_t)BB * TT * HH + (size_t)b_e * HH + j_e] = h;                 // final h
      out[(size_t)BB * TT * HH + BB * HH + (size_t)b_e * HH + j_e] = c_reg;   // final c
    }
    cur ^= 1;
    __threadfence();
    grid.sync();
  }
}

// ---------------- launcher ----------------

extern "C" void kernel_launch(void* const* d_in, const int* in_sizes, int n_in,
                              void* d_out, int out_size, void* d_ws, size_t ws_size,
                              hipStream_t stream) {
  (void)in_sizes; (void)n_in; (void)out_size; (void)ws_size;
  const float* inputs = (const float*)d_in[0];
  const float* h0 = (const float*)d_in[1];
  const float* c0 = (const float*)d_in[2];
  const float* w_ii = (const float*)d_in[3];
  const float* w_hi = (const float*)d_in[4];
  const float* b_ii = (const float*)d_in[5];
  const float* b_hi = (const float*)d_in[6];
  const float* w_if = (const float*)d_in[7];
  const float* w_hf = (const float*)d_in[8];
  const float* b_if = (const float*)d_in[9];
  const float* b_hf = (const float*)d_in[10];
  const float* w_io = (const float*)d_in[11];
  const float* w_ho = (const float*)d_in[12];
  const float* b_io = (const float*)d_in[13];
  const float* b_ho = (const float*)d_in[14];
  const float* w_ig = (const float*)d_in[15];
  const float* w_hg = (const float*)d_in[16];
  const float* b_ig = (const float*)d_in[17];
  const float* b_hg = (const float*)d_in[18];

  char* ws = (char*)d_ws;
  __hip_bfloat16* xb    = (__hip_bfloat16*)ws;                    // 16,777,216 B
  __hip_bfloat16* Wp    = (__hip_bfloat16*)(ws + 16777216);       // 10,485,760 B
  float*          biasp = (float*)(ws + 27262976);                // 16,384 B
  __hip_bfloat16* hbuf  = (__hip_bfloat16*)(ws + 27279360);       // 262,144 B
  float* out = (float*)d_out;

  k_cast_inputs<<<8192, 256, 0, stream>>>(inputs, xb);
  k_pack_w<<<5120, 256, 0, stream>>>(w_ii, w_hi, w_if, w_hf, w_ig, w_hg, w_io, w_ho, Wp);
  k_pack_bias_h0<<<256, 256, 0, stream>>>(b_ii, b_hi, b_if, b_hf, b_ig, b_hg,
                                          b_io, b_ho, h0, biasp, hbuf);

  void* args[] = {(void*)&xb, (void*)&Wp, (void*)&biasp, (void*)&c0,
                  (void*)&hbuf, (void*)&out};
  hipLaunchCooperativeKernel((void*)k_lstm, dim3(NWG), dim3(256), args, 0, stream);
}

// Round 2
// 5243.140 us; speedup vs baseline: 5.9334x; 5.9334x over previous
//
#include <hip/hip_runtime.h>
#include <hip/hip_bf16.h>

#define TT 512
#define BB 64
#define II 256
#define HH 1024
#define NJ 4            // hidden units per WG
#define ROWS 16         // gate rows per WG (4 gates * NJ)
#define KTOT 1280       // 256 (x) + 1024 (h)
#define NWG 256
#define WROW_B 2560     // bytes per LDS weight row (1280 bf16, no pad; XOR-swizzled)

typedef __bf16 bf16x8 __attribute__((ext_vector_type(8)));
typedef float f32x4 __attribute__((ext_vector_type(4)));
typedef unsigned uint32x4 __attribute__((ext_vector_type(4)));

// device-scope (sc1) 16B load: coherent at the device coherence point, bypasses stale L2
__device__ inline uint32x4 ld16_sc1(const void* p) {
  uint32x4 r;
  asm volatile("global_load_dwordx4 %0, %1, off sc1" : "=&v"(r) : "v"(p));
  return r;
}

// ---------------- prep kernels ----------------

__global__ __launch_bounds__(256) void k_cast_inputs(const float* __restrict__ in,
                                                     __hip_bfloat16* __restrict__ outp) {
  int i = (blockIdx.x * 256 + threadIdx.x) * 4;   // grid covers exactly B*T*I
  float4 v = *reinterpret_cast<const float4*>(in + i);
  outp[i + 0] = __float2bfloat16(v.x);
  outp[i + 1] = __float2bfloat16(v.y);
  outp[i + 2] = __float2bfloat16(v.z);
  outp[i + 3] = __float2bfloat16(v.w);
}

// Pack W rows: packed row p = wg*16 + gate*4 + jj  (j = wg*4 + jj), cols [0:256)=Wx, [256:1280)=Wh
__global__ __launch_bounds__(256) void k_pack_w(
    const float* __restrict__ wxi, const float* __restrict__ whi,
    const float* __restrict__ wxf, const float* __restrict__ whf,
    const float* __restrict__ wxg, const float* __restrict__ whg,
    const float* __restrict__ wxo, const float* __restrict__ who,
    __hip_bfloat16* __restrict__ Wp) {
  int t = blockIdx.x * 256 + threadIdx.x;   // 0 .. 4096*320
  int p = t / 320;
  int k4 = (t - p * 320) * 4;
  int wg = p >> 4, loc = p & 15, gate = loc >> 2, jj = loc & 3;
  int j = wg * NJ + jj;
  const float* wx = (gate == 0) ? wxi : (gate == 1) ? wxf : (gate == 2) ? wxg : wxo;
  const float* wh = (gate == 0) ? whi : (gate == 1) ? whf : (gate == 2) ? whg : who;
  float4 v;
  if (k4 < II) v = *reinterpret_cast<const float4*>(wx + (size_t)j * II + k4);
  else         v = *reinterpret_cast<const float4*>(wh + (size_t)j * HH + (k4 - II));
  __hip_bfloat16* o = Wp + (size_t)p * KTOT + k4;
  o[0] = __float2bfloat16(v.x);
  o[1] = __float2bfloat16(v.y);
  o[2] = __float2bfloat16(v.z);
  o[3] = __float2bfloat16(v.w);
}

__global__ __launch_bounds__(256) void k_pack_bias_h0(
    const float* __restrict__ bii, const float* __restrict__ bhi,
    const float* __restrict__ bif, const float* __restrict__ bhf,
    const float* __restrict__ bg,  const float* __restrict__ bhg,
    const float* __restrict__ bio, const float* __restrict__ bho,
    const float* __restrict__ h0, float* __restrict__ biasp,
    __hip_bfloat16* __restrict__ hb, unsigned* __restrict__ flags) {
  int i = blockIdx.x * 256 + threadIdx.x;   // 0..65535
  if (i < 4096) {
    int wg = i >> 4, loc = i & 15, gate = loc >> 2, jj = loc & 3;
    int j = wg * NJ + jj;
    const float* bi = (gate == 0) ? bii : (gate == 1) ? bif : (gate == 2) ? bg : bio;
    const float* bh = (gate == 0) ? bhi : (gate == 1) ? bhf : (gate == 2) ? bhg : bho;
    biasp[i] = bi[j] + bh[j];
  }
  if (i < NWG) flags[i] = 0;                // barrier flags must start at 0 every call
  hb[i] = __float2bfloat16(h0[i]);          // h0 is (1,B,H) = 65536 elems
}

// ---------------- persistent recurrent kernel ----------------
// 256 WGs x 256 threads, cooperative (co-residency). WG wg owns hidden j in
// [wg*4, wg*4+4) = packed gate rows [wg*16, wg*16+16), weights LDS-resident.
// Per step: z = [x_t ; h] @ Wslice^T via MFMA; gate math; c in regs.
// h ping-pong exchanged ONLY via device-scope (sc1) loads/stores — no cache
// flushes. Grid barrier = per-WG flag store (sc1) + wave0 polling all flags.

__global__ __launch_bounds__(256) void k_lstm(
    const __hip_bfloat16* __restrict__ xb,   // (B,T,I) bf16
    const __hip_bfloat16* __restrict__ Wp,   // (4096,1280) packed bf16
    const float* __restrict__ biasp,         // (4096)
    const float* __restrict__ c0,            // (B,H) f32
    __hip_bfloat16* __restrict__ hbuf,       // 2 x (B,H) bf16 ping-pong
    unsigned* __restrict__ flags,            // (NWG) barrier flags
    float* __restrict__ out)                 // hidden(B,T,H) + h(B,H) + c(B,H)
{
  __shared__ __align__(16) char Wl[ROWS * WROW_B];   // 40960 B, XOR-swizzled rows
  __shared__ float zl[BB][ROWS + 1];                 // 4352 B

  const int wg = blockIdx.x;
  const int tid = threadIdx.x;
  const int lane = tid & 63;
  const int wave = tid >> 6;

  // stage this WG's 16 weight rows into LDS (once), 16B units XOR-swizzled by row
  const __hip_bfloat16* Wsrc = Wp + (size_t)wg * ROWS * KTOT;
  for (int v = tid; v < ROWS * (KTOT / 8); v += 256) {
    int r = v / (KTOT / 8);
    int u = v - r * (KTOT / 8);             // 16B unit index 0..159
    *reinterpret_cast<uint4*>(Wl + r * WROW_B + ((u ^ (r & 7)) << 4)) =
        *reinterpret_cast<const uint4*>(Wsrc + (size_t)r * KTOT + u * 8);
  }

  // epilogue identity: thread -> one (batch, jj) cell
  const int b_e = tid >> 2;        // 0..63
  const int jj_e = tid & 3;        // 0..3
  const int j_e = wg * NJ + jj_e;  // global hidden index
  float c_reg = c0[b_e * HH + j_e];
  const float bias_i = biasp[wg * ROWS + 0 * NJ + jj_e];
  const float bias_f = biasp[wg * ROWS + 1 * NJ + jj_e];
  const float bias_g = biasp[wg * ROWS + 2 * NJ + jj_e];
  const float bias_o = biasp[wg * ROWS + 3 * NJ + jj_e];

  // MFMA lane geometry (16x16x32: A row=lane&15, k=8*(lane>>4)+e; D col=lane&15, row=4*(lane>>4)+reg)
  const int mrow = wave * 16 + (lane & 15);      // batch row of A
  const int kqu = (lane >> 4);                   // k sub-offset in 16B units
  const int ncol = lane & 15;                    // gate-row (B column)
  const int drow0 = wave * 16 + kqu * 4;         // D row base
  const int swz = ncol & 7;
  const char* wbase = Wl + ncol * WROW_B;

  const __hip_bfloat16* xrow = xb + (size_t)mrow * (TT * II);

  __syncthreads();

  int cur = 0;
  for (int t = 0; t < TT; ++t) {
    // ---- load fragments ----
    const __hip_bfloat16* xp = xrow + t * II + kqu * 8;
    const __hip_bfloat16* hp = hbuf + cur * (BB * HH) + mrow * HH + kqu * 8;

    bf16x8 xa[8];
    #pragma unroll
    for (int kk = 0; kk < 8; ++kk)
      xa[kk] = *reinterpret_cast<const bf16x8*>(xp + kk * 32);

    uint32x4 hr[32];
    #pragma unroll
    for (int kk = 0; kk < 32; ++kk)
      hr[kk] = ld16_sc1(hp + kk * 32);
    asm volatile("s_waitcnt vmcnt(0)" ::: "memory");
    __builtin_amdgcn_sched_barrier(0);

    // ---- MFMA: z = [x;h] @ W^T ----
    f32x4 accs[4];
    #pragma unroll
    for (int q = 0; q < 4; ++q) accs[q] = (f32x4){0.f, 0.f, 0.f, 0.f};

    #pragma unroll
    for (int kk = 0; kk < 8; ++kk) {
      int u = kk * 4 + kqu;
      bf16x8 b = *reinterpret_cast<const bf16x8*>(wbase + ((u ^ swz) << 4));
      accs[kk & 3] = __builtin_amdgcn_mfma_f32_16x16x32_bf16(xa[kk], b, accs[kk & 3], 0, 0, 0);
    }
    #pragma unroll
    for (int kk = 0; kk < 32; ++kk) {
      int u = 32 + kk * 4 + kqu;
      bf16x8 b = *reinterpret_cast<const bf16x8*>(wbase + ((u ^ swz) << 4));
      bf16x8 a = __builtin_bit_cast(bf16x8, hr[kk]);
      accs[kk & 3] = __builtin_amdgcn_mfma_f32_16x16x32_bf16(a, b, accs[kk & 3], 0, 0, 0);
    }
    f32x4 acc = (accs[0] + accs[1]) + (accs[2] + accs[3]);

    #pragma unroll
    for (int r = 0; r < 4; ++r) zl[drow0 + r][ncol] = acc[r];
    __syncthreads();

    // ---- gate math: one thread per (b, jj) ----
    float zi = zl[b_e][0 + jj_e] + bias_i;
    float zf = zl[b_e][4 + jj_e] + bias_f;
    float zg = zl[b_e][8 + jj_e] + bias_g;
    float zo = zl[b_e][12 + jj_e] + bias_o;
    float ig = 1.f / (1.f + __expf(-zi));
    float fg = 1.f / (1.f + __expf(-zf));
    float gg = 2.f / (1.f + __expf(-2.f * zg)) - 1.f;   // tanh
    float og = 1.f / (1.f + __expf(-zo));
    c_reg = fg * c_reg + ig * gg;
    float tc = 2.f / (1.f + __expf(-2.f * c_reg)) - 1.f;
    float h = og * tc;

    out[(size_t)b_e * (TT * HH) + (size_t)t * HH + j_e] = h;

    if (t == TT - 1) {
      out[(size_t)BB * TT * HH + (size_t)b_e * HH + j_e] = h;                 // final h
      out[(size_t)BB * TT * HH + BB * HH + (size_t)b_e * HH + j_e] = c_reg;   // final c
      break;
    }

    // ---- publish h(t+1) at device scope ----
    __hip_bfloat16 hb16 = __float2bfloat16(h);
    unsigned huv = *reinterpret_cast<unsigned short*>(&hb16);
    const __hip_bfloat16* hw = hbuf + (cur ^ 1) * (BB * HH) + b_e * HH + j_e;
    asm volatile("global_store_short %0, %1, off sc1" :: "v"(hw), "v"(huv) : "memory");
    asm volatile("s_waitcnt vmcnt(0)" ::: "memory");
    __syncthreads();                        // all this WG's h stores at coherence point

    // ---- flag barrier: arrive ----
    if (tid == 0) {
      unsigned gen = (unsigned)t + 1u;
      asm volatile("global_store_dword %0, %1, off sc1" :: "v"(flags + wg), "v"(gen) : "memory");
    }
    // ---- flag barrier: wait (wave 0 polls all 256 flags) ----
    if (wave == 0) {
      const unsigned target = (unsigned)t + 1u;
      uint32x4 f;
      int ok;
      do {
        asm volatile("global_load_dwordx4 %0, %1, off sc1\n\ts_waitcnt vmcnt(0)"
                     : "=&v"(f) : "v"(flags + lane * 4) : "memory");
        ok = (f.x >= target) && (f.y >= target) && (f.z >= target) && (f.w >= target);
      } while (!__all(ok));
    }
    __syncthreads();
    __builtin_amdgcn_sched_barrier(0);
    cur ^= 1;
  }
}

// ---------------- launcher ----------------

extern "C" void kernel_launch(void* const* d_in, const int* in_sizes, int n_in,
                              void* d_out, int out_size, void* d_ws, size_t ws_size,
                              hipStream_t stream) {
  (void)in_sizes; (void)n_in; (void)out_size; (void)ws_size;
  const float* inputs = (const float*)d_in[0];
  const float* h0 = (const float*)d_in[1];
  const float* c0 = (const float*)d_in[2];
  const float* w_ii = (const float*)d_in[3];
  const float* w_hi = (const float*)d_in[4];
  const float* b_ii = (const float*)d_in[5];
  const float* b_hi = (const float*)d_in[6];
  const float* w_if = (const float*)d_in[7];
  const float* w_hf = (const float*)d_in[8];
  const float* b_if = (const float*)d_in[9];
  const float* b_hf = (const float*)d_in[10];
  const float* w_io = (const float*)d_in[11];
  const float* w_ho = (const float*)d_in[12];
  const float* b_io = (const float*)d_in[13];
  const float* b_ho = (const float*)d_in[14];
  const float* w_ig = (const float*)d_in[15];
  const float* w_hg = (const float*)d_in[16];
  const float* b_ig = (const float*)d_in[17];
  const float* b_hg = (const float*)d_in[18];

  char* ws = (char*)d_ws;
  __hip_bfloat16* xb    = (__hip_bfloat16*)ws;                    // 16,777,216 B
  __hip_bfloat16* Wp    = (__hip_bfloat16*)(ws + 16777216);       // 10,485,760 B
  float*          biasp = (float*)(ws + 27262976);                // 16,384 B
  __hip_bfloat16* hbuf  = (__hip_bfloat16*)(ws + 27279360);       // 262,144 B
  unsigned*       flags = (unsigned*)(ws + 27541504);             // 1,024 B
  float* out = (float*)d_out;

  k_cast_inputs<<<8192, 256, 0, stream>>>(inputs, xb);
  k_pack_w<<<5120, 256, 0, stream>>>(w_ii, w_hi, w_if, w_hf, w_ig, w_hg, w_io, w_ho, Wp);
  k_pack_bias_h0<<<256, 256, 0, stream>>>(b_ii, b_hi, b_if, b_hf, b_ig, b_hg,
                                          b_io, b_ho, h0, biasp, hbuf, flags);

  void* args[] = {(void*)&xb, (void*)&Wp, (void*)&biasp, (void*)&c0,
                  (void*)&hbuf, (void*)&flags, (void*)&out};
  hipLaunchCooperativeKernel((void*)k_lstm, dim3(NWG), dim3(256), args, 0, stream);
}

// Round 3
// 4187.584 us; speedup vs baseline: 7.4291x; 1.2521x over previous
//
#include <hip/hip_runtime.h>
#include <hip/hip_bf16.h>

#define TT 512
#define BB 64
#define II 256
#define HH 1024
#define NJ 4            // hidden units per WG
#define ROWS 16         // gate rows per WG (4 gates * NJ)
#define KTOT 1280       // 256 (x) + 1024 (h)
#define NWG 256
#define WROW_B 2560     // bytes per LDS weight row (1280 bf16, XOR-swizzled 16B units)

typedef __bf16 bf16x8 __attribute__((ext_vector_type(8)));
typedef float f32x4 __attribute__((ext_vector_type(4)));
typedef unsigned uint32x4 __attribute__((ext_vector_type(4)));

// write-through stores at device coherence point (no dirty L2 lines — required
// because we buffer_inv every step)
__device__ inline void st16_sc1(void* p, unsigned v) {
  asm volatile("global_store_short %0, %1, off sc1" :: "v"(p), "v"(v) : "memory");
}
__device__ inline void st32_sc1(void* p, float v) {
  asm volatile("global_store_dword %0, %1, off sc1" :: "v"(p), "v"(v) : "memory");
}

// ---------------- prep kernels ----------------

__global__ __launch_bounds__(256) void k_cast_inputs(const float* __restrict__ in,
                                                     __hip_bfloat16* __restrict__ outp) {
  int i = (blockIdx.x * 256 + threadIdx.x) * 4;   // grid covers exactly B*T*I
  float4 v = *reinterpret_cast<const float4*>(in + i);
  outp[i + 0] = __float2bfloat16(v.x);
  outp[i + 1] = __float2bfloat16(v.y);
  outp[i + 2] = __float2bfloat16(v.z);
  outp[i + 3] = __float2bfloat16(v.w);
}

// Pack W rows: packed row p = wg*16 + gate*4 + jj  (j = wg*4 + jj), cols [0:256)=Wx, [256:1280)=Wh
__global__ __launch_bounds__(256) void k_pack_w(
    const float* __restrict__ wxi, const float* __restrict__ whi,
    const float* __restrict__ wxf, const float* __restrict__ whf,
    const float* __restrict__ wxg, const float* __restrict__ whg,
    const float* __restrict__ wxo, const float* __restrict__ who,
    __hip_bfloat16* __restrict__ Wp) {
  int t = blockIdx.x * 256 + threadIdx.x;   // 0 .. 4096*320
  int p = t / 320;
  int k4 = (t - p * 320) * 4;
  int wg = p >> 4, loc = p & 15, gate = loc >> 2, jj = loc & 3;
  int j = wg * NJ + jj;
  const float* wx = (gate == 0) ? wxi : (gate == 1) ? wxf : (gate == 2) ? wxg : wxo;
  const float* wh = (gate == 0) ? whi : (gate == 1) ? whf : (gate == 2) ? whg : who;
  float4 v;
  if (k4 < II) v = *reinterpret_cast<const float4*>(wx + (size_t)j * II + k4);
  else         v = *reinterpret_cast<const float4*>(wh + (size_t)j * HH + (k4 - II));
  __hip_bfloat16* o = Wp + (size_t)p * KTOT + k4;
  o[0] = __float2bfloat16(v.x);
  o[1] = __float2bfloat16(v.y);
  o[2] = __float2bfloat16(v.z);
  o[3] = __float2bfloat16(v.w);
}

__global__ __launch_bounds__(256) void k_pack_bias_h0(
    const float* __restrict__ bii, const float* __restrict__ bhi,
    const float* __restrict__ bif, const float* __restrict__ bhf,
    const float* __restrict__ bg,  const float* __restrict__ bhg,
    const float* __restrict__ bio, const float* __restrict__ bho,
    const float* __restrict__ h0, float* __restrict__ biasp,
    __hip_bfloat16* __restrict__ hb, unsigned* __restrict__ flags) {
  int i = blockIdx.x * 256 + threadIdx.x;   // 0..65535
  if (i < 4096) {
    int wg = i >> 4, loc = i & 15, gate = loc >> 2, jj = loc & 3;
    int j = wg * NJ + jj;
    const float* bi = (gate == 0) ? bii : (gate == 1) ? bif : (gate == 2) ? bg : bio;
    const float* bh = (gate == 0) ? bhi : (gate == 1) ? bhf : (gate == 2) ? bhg : bho;
    biasp[i] = bi[j] + bh[j];
  }
  if (i < NWG) flags[i] = 0;                // barrier flags must start at 0 every call
  hb[i] = __float2bfloat16(h0[i]);          // h0 is (1,B,H) = 65536 elems
}

// ---------------- persistent recurrent kernel ----------------
// 256 WGs x 256 threads, cooperative. Per step:
//   z = [x_t ; h] @ Wslice^T (MFMA, weights LDS-resident, x prefetched to regs)
//   gate math; c in regs; publish h via sc1 write-through; flag barrier (sc1);
//   buffer_inv sc0 sc1; then NORMAL cacheable h loads -> first toucher per XCD
//   pulls from MALL, rest hit the shared L2. No dirty L2 lines anywhere.

__global__ __launch_bounds__(256) void k_lstm(
    const __hip_bfloat16* __restrict__ xb,   // (B,T,I) bf16
    const __hip_bfloat16* __restrict__ Wp,   // (4096,1280) packed bf16
    const float* __restrict__ biasp,         // (4096)
    const float* __restrict__ c0,            // (B,H) f32
    __hip_bfloat16* __restrict__ hbuf,       // 2 x (B,H) bf16 ping-pong
    unsigned* __restrict__ flags,            // (NWG) barrier flags
    float* __restrict__ out)                 // hidden(B,T,H) + h(B,H) + c(B,H)
{
  __shared__ __align__(16) char Wl[ROWS * WROW_B];   // 40960 B, XOR-swizzled rows
  __shared__ float zl[BB][ROWS + 1];                 // 4352 B

  const int wg = blockIdx.x;
  const int tid = threadIdx.x;
  const int lane = tid & 63;
  const int wave = tid >> 6;

  // stage this WG's 16 weight rows into LDS (once), 16B units XOR-swizzled by row
  const __hip_bfloat16* Wsrc = Wp + (size_t)wg * ROWS * KTOT;
  for (int v = tid; v < ROWS * (KTOT / 8); v += 256) {
    int r = v / (KTOT / 8);
    int u = v - r * (KTOT / 8);             // 16B unit index 0..159
    *reinterpret_cast<uint4*>(Wl + r * WROW_B + ((u ^ (r & 7)) << 4)) =
        *reinterpret_cast<const uint4*>(Wsrc + (size_t)r * KTOT + u * 8);
  }

  // epilogue identity: thread -> one (batch, jj) cell
  const int b_e = tid >> 2;        // 0..63
  const int jj_e = tid & 3;        // 0..3
  const int j_e = wg * NJ + jj_e;  // global hidden index
  float c_reg = c0[b_e * HH + j_e];
  const float bias_i = biasp[wg * ROWS + 0 * NJ + jj_e];
  const float bias_f = biasp[wg * ROWS + 1 * NJ + jj_e];
  const float bias_g = biasp[wg * ROWS + 2 * NJ + jj_e];
  const float bias_o = biasp[wg * ROWS + 3 * NJ + jj_e];

  // MFMA lane geometry (16x16x32: A row=lane&15, k=8*(lane>>4)+e; D col=lane&15, row=4*(lane>>4)+reg)
  const int mrow = wave * 16 + (lane & 15);      // batch row of A
  const int kqu = (lane >> 4);                   // k sub-offset in 16B units
  const int ncol = lane & 15;                    // gate-row (B column)
  const int drow0 = wave * 16 + kqu * 4;         // D row base
  const int swz = ncol & 7;
  const char* wbase = Wl + ncol * WROW_B;

  const __hip_bfloat16* xrow = xb + (size_t)mrow * (TT * II);

  __syncthreads();

  // preload x fragments for t=0
  bf16x8 xa[8];
  #pragma unroll
  for (int kk = 0; kk < 8; ++kk)
    xa[kk] = *reinterpret_cast<const bf16x8*>(xrow + kqu * 8 + kk * 32);

  int cur = 0;
  for (int t = 0; t < TT; ++t) {
    // ---- h fragment loads: NORMAL cacheable (L2 fresh: inv'd at end of prev step) ----
    const __hip_bfloat16* hp = hbuf + cur * (BB * HH) + mrow * HH + kqu * 8;
    bf16x8 ha[32];
    #pragma unroll
    for (int kk = 0; kk < 32; ++kk)
      ha[kk] = *reinterpret_cast<const bf16x8*>(hp + kk * 32);

    // ---- MFMA: z = [x;h] @ W^T  (x part first: operands already in regs/LDS) ----
    f32x4 accs[4];
    #pragma unroll
    for (int q = 0; q < 4; ++q) accs[q] = (f32x4){0.f, 0.f, 0.f, 0.f};

    #pragma unroll
    for (int kk = 0; kk < 8; ++kk) {
      int u = kk * 4 + kqu;
      bf16x8 b = *reinterpret_cast<const bf16x8*>(wbase + ((u ^ swz) << 4));
      accs[kk & 3] = __builtin_amdgcn_mfma_f32_16x16x32_bf16(xa[kk], b, accs[kk & 3], 0, 0, 0);
    }
    #pragma unroll
    for (int kk = 0; kk < 32; ++kk) {
      int u = 32 + kk * 4 + kqu;
      bf16x8 b = *reinterpret_cast<const bf16x8*>(wbase + ((u ^ swz) << 4));
      accs[kk & 3] = __builtin_amdgcn_mfma_f32_16x16x32_bf16(ha[kk], b, accs[kk & 3], 0, 0, 0);
    }
    f32x4 acc = (accs[0] + accs[1]) + (accs[2] + accs[3]);

    #pragma unroll
    for (int r = 0; r < 4; ++r) zl[drow0 + r][ncol] = acc[r];
    __syncthreads();

    // ---- gate math: one thread per (b, jj) ----
    float zi = zl[b_e][0 + jj_e] + bias_i;
    float zf = zl[b_e][4 + jj_e] + bias_f;
    float zg = zl[b_e][8 + jj_e] + bias_g;
    float zo = zl[b_e][12 + jj_e] + bias_o;
    float ig = 1.f / (1.f + __expf(-zi));
    float fg = 1.f / (1.f + __expf(-zf));
    float gg = 2.f / (1.f + __expf(-2.f * zg)) - 1.f;   // tanh
    float og = 1.f / (1.f + __expf(-zo));
    c_reg = fg * c_reg + ig * gg;
    float tc = 2.f / (1.f + __expf(-2.f * c_reg)) - 1.f;
    float h = og * tc;

    if (t == TT - 1) {
      st32_sc1(out + (size_t)b_e * (TT * HH) + (size_t)t * HH + j_e, h);
      st32_sc1(out + (size_t)BB * TT * HH + (size_t)b_e * HH + j_e, h);               // final h
      st32_sc1(out + (size_t)BB * TT * HH + BB * HH + (size_t)b_e * HH + j_e, c_reg); // final c
      break;
    }

    // ---- publish h(t+1) at device scope (write-through) ----
    __hip_bfloat16 hb16 = __float2bfloat16(h);
    st16_sc1((void*)(hbuf + (cur ^ 1) * (BB * HH) + b_e * HH + j_e),
             (unsigned)*reinterpret_cast<unsigned short*>(&hb16));
    asm volatile("s_waitcnt vmcnt(0)" ::: "memory");
    __syncthreads();                        // all this WG's h stores at coherence point

    // ---- flag barrier: arrive ----
    if (tid == 0) {
      unsigned gen = (unsigned)t + 1u;
      asm volatile("global_store_dword %0, %1, off sc1" :: "v"(flags + wg), "v"(gen) : "memory");
    }

    // ---- overlap with the poll: hidden-seq store + next-step x prefetch ----
    st32_sc1(out + (size_t)b_e * (TT * HH) + (size_t)t * HH + j_e, h);
    {
      const __hip_bfloat16* xp = xrow + (t + 1) * II + kqu * 8;
      #pragma unroll
      for (int kk = 0; kk < 8; ++kk)
        xa[kk] = *reinterpret_cast<const bf16x8*>(xp + kk * 32);
    }

    // ---- flag barrier: wait (wave 0 polls all 256 flags), then invalidate caches ----
    if (wave == 0) {
      const unsigned target = (unsigned)t + 1u;
      uint32x4 f;
      int ok;
      do {
        asm volatile("global_load_dwordx4 %0, %1, off sc1\n\ts_waitcnt vmcnt(0)"
                     : "=&v"(f) : "v"(flags + lane * 4) : "memory");
        ok = (f.x >= target) && (f.y >= target) && (f.z >= target) && (f.w >= target);
      } while (!__all(ok));
      // discard (clean) stale h lines in L1 + this XCD's L2; fresh h is in MALL
      asm volatile("buffer_inv sc0 sc1" ::: "memory");
      asm volatile("s_waitcnt vmcnt(0)" ::: "memory");
    }
    __syncthreads();
    __builtin_amdgcn_sched_barrier(0);
    cur ^= 1;
  }
}

// ---------------- launcher ----------------

extern "C" void kernel_launch(void* const* d_in, const int* in_sizes, int n_in,
                              void* d_out, int out_size, void* d_ws, size_t ws_size,
                              hipStream_t stream) {
  (void)in_sizes; (void)n_in; (void)out_size; (void)ws_size;
  const float* inputs = (const float*)d_in[0];
  const float* h0 = (const float*)d_in[1];
  const float* c0 = (const float*)d_in[2];
  const float* w_ii = (const float*)d_in[3];
  const float* w_hi = (const float*)d_in[4];
  const float* b_ii = (const float*)d_in[5];
  const float* b_hi = (const float*)d_in[6];
  const float* w_if = (const float*)d_in[7];
  const float* w_hf = (const float*)d_in[8];
  const float* b_if = (const float*)d_in[9];
  const float* b_hf = (const float*)d_in[10];
  const float* w_io = (const float*)d_in[11];
  const float* w_ho = (const float*)d_in[12];
  const float* b_io = (const float*)d_in[13];
  const float* b_ho = (const float*)d_in[14];
  const float* w_ig = (const float*)d_in[15];
  const float* w_hg = (const float*)d_in[16];
  const float* b_ig = (const float*)d_in[17];
  const float* b_hg = (const float*)d_in[18];

  char* ws = (char*)d_ws;
  __hip_bfloat16* xb    = (__hip_bfloat16*)ws;                    // 16,777,216 B
  __hip_bfloat16* Wp    = (__hip_bfloat16*)(ws + 16777216);       // 10,485,760 B
  float*          biasp = (float*)(ws + 27262976);                // 16,384 B
  __hip_bfloat16* hbuf  = (__hip_bfloat16*)(ws + 27279360);       // 262,144 B
  unsigned*       flags = (unsigned*)(ws + 27541504);             // 1,024 B
  float* out = (float*)d_out;

  k_cast_inputs<<<8192, 256, 0, stream>>>(inputs, xb);
  k_pack_w<<<5120, 256, 0, stream>>>(w_ii, w_hi, w_if, w_hf, w_ig, w_hg, w_io, w_ho, Wp);
  k_pack_bias_h0<<<256, 256, 0, stream>>>(b_ii, b_hi, b_if, b_hf, b_ig, b_hg,
                                          b_io, b_ho, h0, biasp, hbuf, flags);

  void* args[] = {(void*)&xb, (void*)&Wp, (void*)&biasp, (void*)&c0,
                  (void*)&hbuf, (void*)&flags, (void*)&out};
  hipLaunchCooperativeKernel((void*)k_lstm, dim3(NWG), dim3(256), args, 0, stream);
}

// Round 4
// 2746.060 us; speedup vs baseline: 11.3289x; 1.5249x over previous
//
#include <hip/hip_runtime.h>
#include <hip/hip_bf16.h>

#define TT 512
#define BB 64
#define II 256
#define HH 1024
#define NWG 256
#define MB 32          // batches per WG
#define NR 32          // packed gate rows per WG (8 hidden units x 4 gates, p = j*4+g)
#define KTOT 1280      // packed weight row: 256 (x) + 1024 (h)
#define ROWB 2048      // bytes per LDS row (1024 bf16)

typedef __bf16 bf16x8 __attribute__((ext_vector_type(8)));
typedef float f32x4 __attribute__((ext_vector_type(4)));
typedef unsigned uint32x4 __attribute__((ext_vector_type(4)));
typedef unsigned uint32x2 __attribute__((ext_vector_type(2)));

__device__ inline uint32x4 ld16_sc1(const void* p) {
  uint32x4 r;
  asm volatile("global_load_dwordx4 %0, %1, off sc1" : "=&v"(r) : "v"(p));
  return r;
}

// ---------------- prep kernels ----------------

__global__ __launch_bounds__(256) void k_cast_inputs(const float* __restrict__ in,
                                                     __hip_bfloat16* __restrict__ outp) {
  int i = (blockIdx.x * 256 + threadIdx.x) * 4;
  float4 v = *reinterpret_cast<const float4*>(in + i);
  outp[i + 0] = __float2bfloat16(v.x);
  outp[i + 1] = __float2bfloat16(v.y);
  outp[i + 2] = __float2bfloat16(v.z);
  outp[i + 3] = __float2bfloat16(v.w);
}

// Packed row p = j*4 + gate (gate order i,f,g,o), cols [0:256)=Wx, [256:1280)=Wh
__global__ __launch_bounds__(256) void k_pack_w(
    const float* __restrict__ wxi, const float* __restrict__ whi,
    const float* __restrict__ wxf, const float* __restrict__ whf,
    const float* __restrict__ wxg, const float* __restrict__ whg,
    const float* __restrict__ wxo, const float* __restrict__ who,
    __hip_bfloat16* __restrict__ Wp) {
  int t = blockIdx.x * 256 + threadIdx.x;   // 0 .. 4096*320
  int p = t / 320;
  int k4 = (t - p * 320) * 4;
  int j = p >> 2, gate = p & 3;
  const float* wx = (gate == 0) ? wxi : (gate == 1) ? wxf : (gate == 2) ? wxg : wxo;
  const float* wh = (gate == 0) ? whi : (gate == 1) ? whf : (gate == 2) ? whg : who;
  float4 v;
  if (k4 < II) v = *reinterpret_cast<const float4*>(wx + (size_t)j * II + k4);
  else         v = *reinterpret_cast<const float4*>(wh + (size_t)j * HH + (k4 - II));
  __hip_bfloat16* o = Wp + (size_t)p * KTOT + k4;
  o[0] = __float2bfloat16(v.x);
  o[1] = __float2bfloat16(v.y);
  o[2] = __float2bfloat16(v.z);
  o[3] = __float2bfloat16(v.w);
}

__global__ __launch_bounds__(256) void k_pack_bias_h0(
    const float* __restrict__ bii, const float* __restrict__ bhi,
    const float* __restrict__ bif, const float* __restrict__ bhf,
    const float* __restrict__ bg,  const float* __restrict__ bhg,
    const float* __restrict__ bio, const float* __restrict__ bho,
    const float* __restrict__ h0, float* __restrict__ biasp,
    __hip_bfloat16* __restrict__ hb, unsigned* __restrict__ flags) {
  int i = blockIdx.x * 256 + threadIdx.x;   // 0..65535
  if (i < 4096) {
    int j = i >> 2, gate = i & 3;
    const float* bi = (gate == 0) ? bii : (gate == 1) ? bif : (gate == 2) ? bg : bio;
    const float* bh = (gate == 0) ? bhi : (gate == 1) ? bhf : (gate == 2) ? bhg : bho;
    biasp[i] = bi[j] + bh[j];
  }
  if (i < NWG) flags[i] = 0;
  hb[i] = __float2bfloat16(h0[i]);
}

// ---------------- persistent recurrent kernel ----------------
// 256 WGs x 256 thr. WG (bt,gt): batches [bt*32,+32), hidden units [gt*8,+8)
// (packed rows [gt*32,+32), p=j*4+g). Wh LDS-resident; Wx in regs; h staged
// into LDS each step via COALESCED sc1 loads (4KB contiguous per instruction).
// Barrier: 2 independent groups of 128 WGs (per batch tile), sc1 flags.

__global__ __launch_bounds__(256, 1) void k_lstm(
    const __hip_bfloat16* __restrict__ xb,
    const __hip_bfloat16* __restrict__ Wp,
    const float* __restrict__ biasp,
    const float* __restrict__ c0,
    __hip_bfloat16* __restrict__ hbuf,    // 2 x (B,H) bf16 ping-pong
    unsigned* __restrict__ flags,         // 256 (2 groups x 128)
    float* __restrict__ out)
{
  extern __shared__ __align__(16) char smem[];
  char* Wl = smem;                       // 65536: Wh rows, XOR-swizzled 16B units
  char* Hs = smem + 65536;               // 65536: staged h, rows=local batch
  char* Zx = smem + 131072;              // 5120: 4 waves * 16 rows * 80B
  char* Ho = smem + 136192;              // 512: h publish bounce [32 b][8 j] bf16

  const int tid = threadIdx.x;
  const int lane = tid & 63;
  const int wave = tid >> 6;
  const int bt = blockIdx.x >> 7;        // batch tile 0..1
  const int gt = blockIdx.x & 127;       // gate tile 0..127
  const int b0 = bt * MB;
  const int r0 = gt * NR;

  const int mh = wave >> 1;              // batch half of wave
  const int nh = wave & 1;               // row half of wave
  const int l15 = lane & 15;
  const int kqu = lane >> 4;             // 0..3 (16B unit within 32-k chunk)

  // ---- prologue: stage Wh -> Wl (coalesced normal loads) ----
  {
    uint32x4 tmp[16];
#pragma unroll
    for (int q = 0; q < 16; ++q) {
      int row = q * 2 + (tid >> 7);
      int u = tid & 127;
      tmp[q] = *reinterpret_cast<const uint32x4*>(Wp + (size_t)(r0 + row) * KTOT + II + u * 8);
    }
#pragma unroll
    for (int q = 0; q < 16; ++q) {
      int row = q * 2 + (tid >> 7);
      int u = tid & 127;
      *reinterpret_cast<uint32x4*>(Wl + row * ROWB + ((u ^ (row & 7)) << 4)) = tmp[q];
    }
  }
  // ---- prologue: stage h(0) -> Hs (coalesced sc1 loads) ----
  {
    uint32x4 tmp[16];
#pragma unroll
    for (int q = 0; q < 16; ++q) {
      int row = q * 2 + (tid >> 7);
      int u = tid & 127;
      tmp[q] = ld16_sc1(hbuf + (size_t)(b0 + row) * HH + u * 8);
    }
    asm volatile("s_waitcnt vmcnt(0)" ::: "memory");
    __builtin_amdgcn_sched_barrier(0);
#pragma unroll
    for (int q = 0; q < 16; ++q) {
      int row = q * 2 + (tid >> 7);
      int u = tid & 127;
      *reinterpret_cast<uint32x4*>(Hs + row * ROWB + ((u ^ (row & 7)) << 4)) = tmp[q];
    }
  }

  // ---- x-part weights in registers: wave's 16 rows ----
  bf16x8 wxr[8];
  {
    const __hip_bfloat16* wsrc = Wp + (size_t)(r0 + nh * 16 + l15) * KTOT + kqu * 8;
#pragma unroll
    for (int kk = 0; kk < 8; ++kk)
      wxr[kk] = *reinterpret_cast<const bf16x8*>(wsrc + kk * 32);
  }

  // ---- epilogue cell identity ----
  const int m_e = 4 * (lane >> 4) + (lane & 3);   // batch offset in wave tile
  const int tq = (lane >> 2) & 3;                 // hidden-unit offset in wave tile
  const int j_l = nh * 4 + tq;                    // 0..7
  const int b_l = mh * 16 + m_e;                  // 0..31
  const int j_g = gt * 8 + j_l;
  const int b_g = b0 + b_l;
  const float4 bias = *reinterpret_cast<const float4*>(biasp + j_g * 4);
  float c_reg = c0[(size_t)b_g * HH + j_g];

  // ---- fragment geometry ----
  const int am_row = mh * 16 + l15, am_swz = am_row & 7;   // A rows (batches)
  const int bn_row = nh * 16 + l15, bn_swz = bn_row & 7;   // B rows (gate rows)
  char* ZxW = Zx + wave * 1280;

  // x fragments for t=0
  const __hip_bfloat16* xrowA = xb + (size_t)(b0 + mh * 16 + l15) * (TT * II) + kqu * 8;
  bf16x8 xa[8];
#pragma unroll
  for (int kk = 0; kk < 8; ++kk)
    xa[kk] = *reinterpret_cast<const bf16x8*>(xrowA + kk * 32);

  __syncthreads();

  int cur = 0;
  for (int t = 0; t < TT; ++t) {
    // ---- A: MFMA z = [x;h] @ W^T ----
    f32x4 accs[4];
#pragma unroll
    for (int q = 0; q < 4; ++q) accs[q] = (f32x4){0.f, 0.f, 0.f, 0.f};
#pragma unroll
    for (int kk = 0; kk < 8; ++kk)
      accs[kk & 3] = __builtin_amdgcn_mfma_f32_16x16x32_bf16(xa[kk], wxr[kk], accs[kk & 3], 0, 0, 0);
#pragma unroll
    for (int kk = 0; kk < 32; ++kk) {
      int u = kk * 4 + kqu;
      bf16x8 a = *reinterpret_cast<const bf16x8*>(Hs + am_row * ROWB + ((u ^ am_swz) << 4));
      bf16x8 b = *reinterpret_cast<const bf16x8*>(Wl + bn_row * ROWB + ((u ^ bn_swz) << 4));
      accs[kk & 3] = __builtin_amdgcn_mfma_f32_16x16x32_bf16(a, b, accs[kk & 3], 0, 0, 0);
    }
    f32x4 acc = (accs[0] + accs[1]) + (accs[2] + accs[3]);

    // ---- B: in-wave z exchange via LDS (cross-lane: explicit fence!) ----
    *reinterpret_cast<f32x4*>(ZxW + l15 * 80 + (lane >> 4) * 16) = acc;
    asm volatile("s_waitcnt lgkmcnt(0)" ::: "memory");
    __builtin_amdgcn_sched_barrier(0);
    float zi = *reinterpret_cast<const float*>(ZxW + (4 * tq + 0) * 80 + m_e * 4) + bias.x;
    float zf = *reinterpret_cast<const float*>(ZxW + (4 * tq + 1) * 80 + m_e * 4) + bias.y;
    float zg = *reinterpret_cast<const float*>(ZxW + (4 * tq + 2) * 80 + m_e * 4) + bias.z;
    float zo = *reinterpret_cast<const float*>(ZxW + (4 * tq + 3) * 80 + m_e * 4) + bias.w;

    float ig = 1.f / (1.f + __expf(-zi));
    float fg = 1.f / (1.f + __expf(-zf));
    float gg = 2.f / (1.f + __expf(-2.f * zg)) - 1.f;
    float og = 1.f / (1.f + __expf(-zo));
    c_reg = fg * c_reg + ig * gg;
    float tc = 2.f / (1.f + __expf(-2.f * c_reg)) - 1.f;
    float h = og * tc;

    out[(size_t)b_g * (TT * HH) + (size_t)t * HH + j_g] = h;

    if (t == TT - 1) {
      out[(size_t)BB * TT * HH + (size_t)b_g * HH + j_g] = h;
      out[(size_t)BB * TT * HH + BB * HH + (size_t)b_g * HH + j_g] = c_reg;
      break;
    }

    // ---- D: h -> Ho bounce ----
    __hip_bfloat16 hb16 = __float2bfloat16(h);
    *reinterpret_cast<unsigned short*>(Ho + b_l * 16 + j_l * 2) =
        *reinterpret_cast<unsigned short*>(&hb16);
    __syncthreads();                      // F: Ho ready; Hs reads done

    const int nxt = cur ^ 1;
    // ---- G: wave0 publishes coalesced + flags ----
    if (wave == 0) {
      if (lane < 32) {
        uint32x4 hv = *reinterpret_cast<const uint32x4*>(Ho + lane * 16);
        __hip_bfloat16* dst = hbuf + (size_t)nxt * (BB * HH) + (size_t)(b0 + lane) * HH + gt * 8;
        asm volatile("global_store_dwordx4 %0, %1, off sc1" :: "v"(dst), "v"(hv) : "memory");
      }
      asm volatile("s_waitcnt vmcnt(0)" ::: "memory");
      if (lane == 0) {
        unsigned gen = (unsigned)t + 1u;
        asm volatile("global_store_dword %0, %1, off sc1"
                     :: "v"(flags + bt * 128 + gt), "v"(gen) : "memory");
      }
    }

    // ---- H: x(t+1) prefetch (overlaps poll) ----
    {
      const __hip_bfloat16* xp = xrowA + (size_t)(t + 1) * II;
#pragma unroll
      for (int kk = 0; kk < 8; ++kk)
        xa[kk] = *reinterpret_cast<const bf16x8*>(xp + kk * 32);
    }

    // ---- I: wave0 polls its group's 128 flags ----
    if (wave == 0) {
      const unsigned target = (unsigned)t + 1u;
      const unsigned* fp = flags + bt * 128 + lane * 2;
      uint32x2 f;
      int ok;
      do {
        asm volatile("global_load_dwordx2 %0, %1, off sc1\n\ts_waitcnt vmcnt(0)"
                     : "=&v"(f) : "v"(fp) : "memory");
        ok = (f.x >= target) && (f.y >= target);
      } while (!__all(ok));
    }
    __syncthreads();                      // J

    // ---- K: stage h(t+1) -> Hs (coalesced sc1) ----
    {
      uint32x4 tmp[16];
      const __hip_bfloat16* hsrc = hbuf + (size_t)nxt * (BB * HH);
#pragma unroll
      for (int q = 0; q < 16; ++q) {
        int row = q * 2 + (tid >> 7);
        int u = tid & 127;
        tmp[q] = ld16_sc1(hsrc + (size_t)(b0 + row) * HH + u * 8);
      }
      asm volatile("s_waitcnt vmcnt(0)" ::: "memory");
      __builtin_amdgcn_sched_barrier(0);
#pragma unroll
      for (int q = 0; q < 16; ++q) {
        int row = q * 2 + (tid >> 7);
        int u = tid & 127;
        *reinterpret_cast<uint32x4*>(Hs + row * ROWB + ((u ^ (row & 7)) << 4)) = tmp[q];
      }
    }
    __syncthreads();                      // L
    cur = nxt;
  }
}

// ---------------- launcher ----------------

extern "C" void kernel_launch(void* const* d_in, const int* in_sizes, int n_in,
                              void* d_out, int out_size, void* d_ws, size_t ws_size,
                              hipStream_t stream) {
  (void)in_sizes; (void)n_in; (void)out_size; (void)ws_size;
  const float* inputs = (const float*)d_in[0];
  const float* h0 = (const float*)d_in[1];
  const float* c0 = (const float*)d_in[2];
  const float* w_ii = (const float*)d_in[3];
  const float* w_hi = (const float*)d_in[4];
  const float* b_ii = (const float*)d_in[5];
  const float* b_hi = (const float*)d_in[6];
  const float* w_if = (const float*)d_in[7];
  const float* w_hf = (const float*)d_in[8];
  const float* b_if = (const float*)d_in[9];
  const float* b_hf = (const float*)d_in[10];
  const float* w_io = (const float*)d_in[11];
  const float* w_ho = (const float*)d_in[12];
  const float* b_io = (const float*)d_in[13];
  const float* b_ho = (const float*)d_in[14];
  const float* w_ig = (const float*)d_in[15];
  const float* w_hg = (const float*)d_in[16];
  const float* b_ig = (const float*)d_in[17];
  const float* b_hg = (const float*)d_in[18];

  char* ws = (char*)d_ws;
  __hip_bfloat16* xb    = (__hip_bfloat16*)ws;                    // 16,777,216 B
  __hip_bfloat16* Wp    = (__hip_bfloat16*)(ws + 16777216);       // 10,485,760 B
  float*          biasp = (float*)(ws + 27262976);                // 16,384 B
  __hip_bfloat16* hbuf  = (__hip_bfloat16*)(ws + 27279360);       // 262,144 B
  unsigned*       flags = (unsigned*)(ws + 27541504);             // 1,024 B
  float* out = (float*)d_out;

  k_cast_inputs<<<8192, 256, 0, stream>>>(inputs, xb);
  k_pack_w<<<5120, 256, 0, stream>>>(w_ii, w_hi, w_if, w_hf, w_ig, w_hg, w_io, w_ho, Wp);
  k_pack_bias_h0<<<256, 256, 0, stream>>>(b_ii, b_hi, b_if, b_hf, b_ig, b_hg,
                                          b_io, b_ho, h0, biasp, hbuf, flags);

  const int lds_bytes = 136704;
  hipFuncSetAttribute((const void*)k_lstm,
                      hipFuncAttributeMaxDynamicSharedMemorySize, lds_bytes);
  void* args[] = {(void*)&xb, (void*)&Wp, (void*)&biasp, (void*)&c0,
                  (void*)&hbuf, (void*)&flags, (void*)&out};
  hipLaunchCooperativeKernel((void*)k_lstm, dim3(NWG), dim3(256), args,
                             lds_bytes, stream);
}

// Round 6
// 2315.696 us; speedup vs baseline: 13.4344x; 1.1858x over previous
//
#include <hip/hip_runtime.h>
#include <hip/hip_bf16.h>

#define TT 512
#define BB 64
#define II 256
#define HH 1024
#define NWG 256
#define MB 32          // batches per WG
#define NR 32          // packed gate rows per WG (8 j x 4 gates, p = j*4+g)
#define KTOT 1280      // packed weight row: 256 (x) + 1024 (h)
#define ROWB 2048      // bytes per LDS row (1024 bf16)
#define NFLAG 1024     // 2 groups x 128 gt x 4 waves

typedef __bf16 bf16x8 __attribute__((ext_vector_type(8)));
typedef float f32x4 __attribute__((ext_vector_type(4)));
typedef unsigned uint32x4 __attribute__((ext_vector_type(4)));
typedef unsigned uint32x2 __attribute__((ext_vector_type(2)));

__device__ inline uint32x4 ld16_sc1(const void* p) {
  uint32x4 r;
  asm volatile("global_load_dwordx4 %0, %1, off sc1" : "=&v"(r) : "v"(p));
  return r;
}

// ---------------- prep kernels ----------------

__global__ __launch_bounds__(256) void k_cast_inputs(const float* __restrict__ in,
                                                     __hip_bfloat16* __restrict__ outp) {
  int i = (blockIdx.x * 256 + threadIdx.x) * 4;
  float4 v = *reinterpret_cast<const float4*>(in + i);
  outp[i + 0] = __float2bfloat16(v.x);
  outp[i + 1] = __float2bfloat16(v.y);
  outp[i + 2] = __float2bfloat16(v.z);
  outp[i + 3] = __float2bfloat16(v.w);
}

// Packed row p = j*4 + gate (gate order i,f,g,o), cols [0:256)=Wx, [256:1280)=Wh
__global__ __launch_bounds__(256) void k_pack_w(
    const float* __restrict__ wxi, const float* __restrict__ whi,
    const float* __restrict__ wxf, const float* __restrict__ whf,
    const float* __restrict__ wxg, const float* __restrict__ whg,
    const float* __restrict__ wxo, const float* __restrict__ who,
    __hip_bfloat16* __restrict__ Wp) {
  int t = blockIdx.x * 256 + threadIdx.x;   // 0 .. 4096*320
  int p = t / 320;
  int k4 = (t - p * 320) * 4;
  int j = p >> 2, gate = p & 3;
  const float* wx = (gate == 0) ? wxi : (gate == 1) ? wxf : (gate == 2) ? wxg : wxo;
  const float* wh = (gate == 0) ? whi : (gate == 1) ? whf : (gate == 2) ? whg : who;
  float4 v;
  if (k4 < II) v = *reinterpret_cast<const float4*>(wx + (size_t)j * II + k4);
  else         v = *reinterpret_cast<const float4*>(wh + (size_t)j * HH + (k4 - II));
  __hip_bfloat16* o = Wp + (size_t)p * KTOT + k4;
  o[0] = __float2bfloat16(v.x);
  o[1] = __float2bfloat16(v.y);
  o[2] = __float2bfloat16(v.z);
  o[3] = __float2bfloat16(v.w);
}

__global__ __launch_bounds__(256) void k_pack_bias_h0(
    const float* __restrict__ bii, const float* __restrict__ bhi,
    const float* __restrict__ bif, const float* __restrict__ bhf,
    const float* __restrict__ bg,  const float* __restrict__ bhg,
    const float* __restrict__ bio, const float* __restrict__ bho,
    const float* __restrict__ h0, float* __restrict__ biasp,
    __hip_bfloat16* __restrict__ hb, unsigned* __restrict__ flags) {
  int i = blockIdx.x * 256 + threadIdx.x;   // 0..65535
  if (i < 4096) {
    int j = i >> 2, gate = i & 3;
    const float* bi = (gate == 0) ? bii : (gate == 1) ? bif : (gate == 2) ? bg : bio;
    const float* bh = (gate == 0) ? bhi : (gate == 1) ? bhf : (gate == 2) ? bhg : bho;
    biasp[i] = bi[j] + bh[j];
  }
  if (i < NFLAG) flags[i] = 0;
  hb[i] = __float2bfloat16(h0[i]);
}

// ---------------- persistent recurrent kernel ----------------
// R4 tiling (proven): 256 WGs x 256 thr. WG (bt,gt): bt=blk>>7 batches
// [bt*32,+32), gt=blk&127 hidden units [gt*8,+8) = packed rows [gt*32,+32).
// Wave wq: mh=wq>>1 batch half, nh=wq&1 row half -> 16x16 MFMA quadrant.
// Wh in LDS (Wl), Wx in regs, h staged in LDS (Hs) via coalesced sc1.
// NEW vs R4 (the one delta): per-WAVE flags/publish/poll/stage; ONE
// __syncthreads per step; x-part MFMA precomputed during the poll window.

__global__ __launch_bounds__(256, 1) void k_lstm(
    const __hip_bfloat16* __restrict__ xb,
    const __hip_bfloat16* __restrict__ Wp,
    const float* __restrict__ biasp,
    const float* __restrict__ c0,
    __hip_bfloat16* __restrict__ hbuf,    // 2 x (B,H) bf16 ping-pong
    unsigned* __restrict__ flags,         // 2 groups x 128 gt x 4 waves
    float* __restrict__ out)
{
  extern __shared__ __align__(16) char smem[];
  char* Wl = smem;                       // 65536: Wh rows, XOR-swizzled 16B units
  char* Hs = smem + 65536;               // 65536: staged h rows (local batches)
  char* Zx = smem + 131072;              // 5120: per-wave z exchange
  char* Ho = smem + 136192;              // 512: per-wave h bounce (4 x 128B)

  const int tid = threadIdx.x;
  const int lane = tid & 63;
  const int wq = tid >> 6;
  const int bt = blockIdx.x >> 7;        // batch group 0..1
  const int gt = blockIdx.x & 127;       // j tile 0..127
  const int b0 = bt * MB;
  const int r0 = gt * NR;

  const int mh = wq >> 1;                // batch half
  const int nh = wq & 1;                 // row half
  const int l15 = lane & 15;
  const int kqu = lane >> 4;             // 0..3 (16B unit within 32-k chunk)

  // ---- prologue: stage Wh -> Wl (coalesced normal loads, 256 threads) ----
  {
    uint32x4 tmp[16];
#pragma unroll
    for (int q = 0; q < 16; ++q) {
      int row = q * 2 + (tid >> 7);
      int u = tid & 127;
      tmp[q] = *reinterpret_cast<const uint32x4*>(Wp + (size_t)(r0 + row) * KTOT + II + u * 8);
    }
#pragma unroll
    for (int q = 0; q < 16; ++q) {
      int row = q * 2 + (tid >> 7);
      int u = tid & 127;
      *reinterpret_cast<uint32x4*>(Wl + row * ROWB + ((u ^ (row & 7)) << 4)) = tmp[q];
    }
  }

  // ---- x-part weights in registers: wave's 16 rows ----
  bf16x8 wxr[8];
  {
    const __hip_bfloat16* wsrc = Wp + (size_t)(r0 + nh * 16 + l15) * KTOT + kqu * 8;
#pragma unroll
    for (int kk = 0; kk < 8; ++kk)
      wxr[kk] = *reinterpret_cast<const bf16x8*>(wsrc + kk * 32);
  }

  // ---- epilogue cell identity ----
  const int m_e = 4 * kqu + (lane & 3);            // batch offset in wave tile
  const int tq = (lane >> 2) & 3;                  // j offset in wave tile
  const int j_l = nh * 4 + tq;                     // 0..7
  const int b_l = mh * 16 + m_e;                   // 0..31
  const int j_g = gt * 8 + j_l;
  const int b_g = b0 + b_l;
  const float4 bias = *reinterpret_cast<const float4*>(biasp + j_g * 4);
  float c_reg = c0[(size_t)b_g * HH + j_g];

  // ---- fragment geometry ----
  const int am_row = mh * 16 + l15, am_swz = am_row & 7;   // A rows (batches)
  const int bn_row = nh * 16 + l15, bn_swz = bn_row & 7;   // B rows (gate rows)
  char* ZxW = Zx + wq * 1280;
  char* HoW = Ho + wq * 128;

  // ---- prologue: per-wave stage h(0) -> Hs rows [wq*8,+8), coalesced sc1 ----
  {
    uint32x4 tmp[16];
#pragma unroll
    for (int q = 0; q < 16; ++q) {
      int idx = q * 64 + lane;                     // 0..1023
      int rl = wq * 8 + (idx >> 7);
      int u = idx & 127;
      tmp[q] = ld16_sc1(hbuf + (size_t)(b0 + rl) * HH + u * 8);
    }
    asm volatile("s_waitcnt vmcnt(0)" ::: "memory");
    __builtin_amdgcn_sched_barrier(0);
#pragma unroll
    for (int q = 0; q < 16; ++q) {
      int idx = q * 64 + lane;
      int rl = wq * 8 + (idx >> 7);
      int u = idx & 127;
      *reinterpret_cast<uint32x4*>(Hs + rl * ROWB + ((u ^ (rl & 7)) << 4)) = tmp[q];
    }
  }

  // ---- prologue: x-part MFMA for t=0 ----
  const __hip_bfloat16* xrowA = xb + (size_t)(b0 + mh * 16 + l15) * (TT * II) + kqu * 8;
  f32x4 accs[4];
#pragma unroll
  for (int q = 0; q < 4; ++q) accs[q] = (f32x4){0.f, 0.f, 0.f, 0.f};
#pragma unroll
  for (int kk = 0; kk < 8; ++kk) {
    bf16x8 xa = *reinterpret_cast<const bf16x8*>(xrowA + kk * 32);
    accs[kk & 3] = __builtin_amdgcn_mfma_f32_16x16x32_bf16(xa, wxr[kk], accs[kk & 3], 0, 0, 0);
  }

  __syncthreads();

  for (int t = 0; t < TT; ++t) {
    // ---- A: h-part MFMA (x-part already in accs) ----
#pragma unroll
    for (int kk = 0; kk < 32; ++kk) {
      int u = kk * 4 + kqu;
      bf16x8 a = *reinterpret_cast<const bf16x8*>(Hs + am_row * ROWB + ((u ^ am_swz) << 4));
      bf16x8 b = *reinterpret_cast<const bf16x8*>(Wl + bn_row * ROWB + ((u ^ bn_swz) << 4));
      accs[kk & 3] = __builtin_amdgcn_mfma_f32_16x16x32_bf16(a, b, accs[kk & 3], 0, 0, 0);
    }
    f32x4 acc = (accs[0] + accs[1]) + (accs[2] + accs[3]);

    // ---- B: in-wave z exchange via LDS (drains step-A LDS reads too) ----
    *reinterpret_cast<f32x4*>(ZxW + l15 * 80 + kqu * 16) = acc;
    asm volatile("s_waitcnt lgkmcnt(0)" ::: "memory");
    __builtin_amdgcn_sched_barrier(0);
    float zi = *reinterpret_cast<const float*>(ZxW + (4 * tq + 0) * 80 + m_e * 4) + bias.x;
    float zf = *reinterpret_cast<const float*>(ZxW + (4 * tq + 1) * 80 + m_e * 4) + bias.y;
    float zg = *reinterpret_cast<const float*>(ZxW + (4 * tq + 2) * 80 + m_e * 4) + bias.z;
    float zo = *reinterpret_cast<const float*>(ZxW + (4 * tq + 3) * 80 + m_e * 4) + bias.w;

    float ig = 1.f / (1.f + __expf(-zi));
    float fg = 1.f / (1.f + __expf(-zf));
    float gg = 2.f / (1.f + __expf(-2.f * zg)) - 1.f;
    float og = 1.f / (1.f + __expf(-zo));
    c_reg = fg * c_reg + ig * gg;
    float tc = 2.f / (1.f + __expf(-2.f * c_reg)) - 1.f;
    float h = og * tc;

    if (t == TT - 1) {
      out[(size_t)b_g * (TT * HH) + (size_t)t * HH + j_g] = h;
      out[(size_t)BB * TT * HH + (size_t)b_g * HH + j_g] = h;
      out[(size_t)BB * TT * HH + BB * HH + (size_t)b_g * HH + j_g] = c_reg;
      break;
    }

    // ---- C: h -> wave-local Ho bounce, publish 8B sc1, per-wave flag ----
    __hip_bfloat16 hb16 = __float2bfloat16(h);
    *reinterpret_cast<unsigned short*>(HoW + m_e * 8 + tq * 2) =
        *reinterpret_cast<unsigned short*>(&hb16);
    asm volatile("s_waitcnt lgkmcnt(0)" ::: "memory");
    __builtin_amdgcn_sched_barrier(0);

    const int nxt = (t + 1) & 1;
    if (lane < 16) {
      uint32x2 hv = *reinterpret_cast<const uint32x2*>(HoW + lane * 8);
      __hip_bfloat16* dst = hbuf + (size_t)nxt * (BB * HH)
                          + (size_t)(b0 + mh * 16 + lane) * HH + gt * 8 + nh * 4;
      asm volatile("global_store_dwordx2 %0, %1, off sc1" :: "v"(dst), "v"(hv) : "memory");
    }
    asm volatile("s_waitcnt vmcnt(0)" ::: "memory");
    if (lane == 0) {
      unsigned gen = (unsigned)t + 1u;
      asm volatile("global_store_dword %0, %1, off sc1"
                   :: "v"(flags + bt * 512 + gt * 4 + wq), "v"(gen) : "memory");
    }

    // ---- D: poll-window work: out store + x(t+1)-part MFMA ----
    out[(size_t)b_g * (TT * HH) + (size_t)t * HH + j_g] = h;
#pragma unroll
    for (int q = 0; q < 4; ++q) accs[q] = (f32x4){0.f, 0.f, 0.f, 0.f};
    {
      const __hip_bfloat16* xp = xrowA + (size_t)(t + 1) * II;
#pragma unroll
      for (int kk = 0; kk < 8; ++kk) {
        bf16x8 xa = *reinterpret_cast<const bf16x8*>(xp + kk * 32);
        accs[kk & 3] = __builtin_amdgcn_mfma_f32_16x16x32_bf16(xa, wxr[kk], accs[kk & 3], 0, 0, 0);
      }
    }

    // ---- E: every wave polls its group's 512 flags (8 per lane) ----
    {
      const unsigned target = (unsigned)t + 1u;
      const unsigned* fp = flags + bt * 512 + lane * 8;
      uint32x4 f1, f2;
      int ok;
      do {
        asm volatile("global_load_dwordx4 %0, %2, off sc1\n\t"
                     "global_load_dwordx4 %1, %3, off sc1\n\t"
                     "s_waitcnt vmcnt(0)"
                     : "=&v"(f1), "=&v"(f2) : "v"(fp), "v"(fp + 4) : "memory");
        ok = (f1.x >= target) && (f1.y >= target) && (f1.z >= target) && (f1.w >= target)
          && (f2.x >= target) && (f2.y >= target) && (f2.z >= target) && (f2.w >= target);
      } while (!__all(ok));
    }

    // ---- F: per-wave stage h(t+1) -> Hs rows [wq*8,+8), coalesced sc1 ----
    {
      uint32x4 tmp[16];
      const __hip_bfloat16* hsrc = hbuf + (size_t)nxt * (BB * HH);
#pragma unroll
      for (int q = 0; q < 16; ++q) {
        int idx = q * 64 + lane;
        int rl = wq * 8 + (idx >> 7);
        int u = idx & 127;
        tmp[q] = ld16_sc1(hsrc + (size_t)(b0 + rl) * HH + u * 8);
      }
      asm volatile("s_waitcnt vmcnt(0)" ::: "memory");
      __builtin_amdgcn_sched_barrier(0);
#pragma unroll
      for (int q = 0; q < 16; ++q) {
        int idx = q * 64 + lane;
        int rl = wq * 8 + (idx >> 7);
        int u = idx & 127;
        *reinterpret_cast<uint32x4*>(Hs + rl * ROWB + ((u ^ (rl & 7)) << 4)) = tmp[q];
      }
    }
    __syncthreads();                     // stage -> fragment-read handoff
  }
}

// ---------------- launcher ----------------

extern "C" void kernel_launch(void* const* d_in, const int* in_sizes, int n_in,
                              void* d_out, int out_size, void* d_ws, size_t ws_size,
                              hipStream_t stream) {
  (void)in_sizes; (void)n_in; (void)out_size; (void)ws_size;
  const float* inputs = (const float*)d_in[0];
  const float* h0 = (const float*)d_in[1];
  const float* c0 = (const float*)d_in[2];
  const float* w_ii = (const float*)d_in[3];
  const float* w_hi = (const float*)d_in[4];
  const float* b_ii = (const float*)d_in[5];
  const float* b_hi = (const float*)d_in[6];
  const float* w_if = (const float*)d_in[7];
  const float* w_hf = (const float*)d_in[8];
  const float* b_if = (const float*)d_in[9];
  const float* b_hf = (const float*)d_in[10];
  const float* w_io = (const float*)d_in[11];
  const float* w_ho = (const float*)d_in[12];
  const float* b_io = (const float*)d_in[13];
  const float* b_ho = (const float*)d_in[14];
  const float* w_ig = (const float*)d_in[15];
  const float* w_hg = (const float*)d_in[16];
  const float* b_ig = (const float*)d_in[17];
  const float* b_hg = (const float*)d_in[18];

  char* ws = (char*)d_ws;
  __hip_bfloat16* xb    = (__hip_bfloat16*)ws;                    // 16,777,216 B
  __hip_bfloat16* Wp    = (__hip_bfloat16*)(ws + 16777216);       // 10,485,760 B
  float*          biasp = (float*)(ws + 27262976);                // 16,384 B
  __hip_bfloat16* hbuf  = (__hip_bfloat16*)(ws + 27279360);       // 262,144 B
  unsigned*       flags = (unsigned*)(ws + 27541504);             // 4,096 B
  float* out = (float*)d_out;

  k_cast_inputs<<<8192, 256, 0, stream>>>(inputs, xb);
  k_pack_w<<<5120, 256, 0, stream>>>(w_ii, w_hi, w_if, w_hf, w_ig, w_hg, w_io, w_ho, Wp);
  k_pack_bias_h0<<<256, 256, 0, stream>>>(b_ii, b_hi, b_if, b_hf, b_ig, b_hg,
                                          b_io, b_ho, h0, biasp, hbuf, flags);

  const int lds_bytes = 136704;
  hipFuncSetAttribute((const void*)k_lstm,
                      hipFuncAttributeMaxDynamicSharedMemorySize, lds_bytes);
  void* args[] = {(void*)&xb, (void*)&Wp, (void*)&biasp, (void*)&c0,
                  (void*)&hbuf, (void*)&flags, (void*)&out};
  hipLaunchCooperativeKernel((void*)k_lstm, dim3(NWG), dim3(256), args,
                             lds_bytes, stream);
}